// Round 3
// baseline (3695.595 us; speedup 1.0000x reference)
//
#include <hip/hip_runtime.h>
#include <stdint.h>

#define LVLS 16
#define TSZ (1u << 19)
#define PR1 2654435761u
#define PR2 805459861u
#define PR3 3674653429u

// ---------------- Fused kernel: encode + last-arriver MLP --------------------
// Encode part is the frozen round-6 kernel (XCD level-pinning, 2 threads/point,
// 8 float2 gathers, pair shfl). After writing its level-slice of chunk c, each
// block bumps counters[c]; the 16th arriver (all levels of chunk c now in
// encbuf, release-fenced) runs the MLP for those 128 points.
// MLP is register-lean to protect encode occupancy: 2 passes x 64 points,
// 1 pt/lane, wave w owns cols [16w,16w+16) (weights stay wave-uniform s_load),
// enc staged cooperatively in LDS (dedups the 4-wave redundant global reads).
// LDS 24.6KB + ~60 VGPR -> 6 blocks/CU (75% occ, vs 77% for pure encode).
// MLP VALU work (~11us aggregate) hides under encode's 89%-idle VALU.
__global__ __launch_bounds__(256, 6) void fused_kernel(
    const float* __restrict__ img, const float* __restrict__ pose,
    const float* __restrict__ table, const float* __restrict__ W1,
    const float* __restrict__ W2, const float* __restrict__ W3,
    float* __restrict__ encbuf, int* __restrict__ counters,
    float* __restrict__ out, int npts, int Bper)
{
    __shared__ __align__(16) char ldsbuf[24 * 1024];
    __shared__ int lastFlag;
    float2 (*encS)[64]    = (float2 (*)[64])ldsbuf;              // [16][64] 8KB
    float  (*h1S)[64]     = (float  (*)[64])(ldsbuf + 8192);     // [64][64] 16KB
    float  (*oS)[64][9]   = (float  (*)[64][9])(ldsbuf + 8192);  // [4][64][9] reuse

    const int bid  = blockIdx.x;
    const int grp  = 8 * Bper;
    const int level = (bid % 8) + 8 * (bid / grp);
    const int chunk = (bid % grp) / 8;
    const int tid  = threadIdx.x;

    // ---------------- encode phase (frozen structure) ----------------
    {
        const int idx = chunk * 256 + tid;
        const int p = idx >> 1;
        const int s = idx & 1;

        const float2 xi = ((const float2*)img)[p];
        const float2 xp = ((const float2*)pose)[p];

        constexpr float resv[LVLS] = {16.f, 22.f, 30.f, 42.f, 58.f, 80.f, 110.f, 152.f,
                                      210.f, 290.f, 400.f, 553.f, 763.f, 1053.f, 1453.f, 2005.f};
        const float rr = resv[level];

        const float s0 = xi.x * rr, s1 = xi.y * rr, s2 = xp.x * rr, s3 = xp.y * rr;
        const float p0f = floorf(s0), p1f = floorf(s1), p2f = floorf(s2), p3f = floorf(s3);
        const float f0 = s0 - p0f, f1 = s1 - p1f, f2 = s2 - p2f, f3 = s3 - p3f;
        const uint32_t q0 = (uint32_t)p0f, q1 = (uint32_t)p1f,
                       q2 = (uint32_t)p2f, q3 = (uint32_t)p3f;

        const uint32_t b0  = q0 + (uint32_t)s;
        const uint32_t h1a = q1 * PR1, h1b = h1a + PR1;
        const uint32_t h2a = q2 * PR2, h2b = h2a + PR2;
        const uint32_t h3a = q3 * PR3, h3b = h3a + PR3;
        const uint32_t loff = (uint32_t)level * TSZ;

        const float2* __restrict__ tab2 = (const float2*)table;

        float2 f[8];
        #pragma unroll
        for (int c = 0; c < 8; ++c) {
            const uint32_t h = b0 ^ ((c & 1) ? h1b : h1a)
                                  ^ ((c & 2) ? h2b : h2a)
                                  ^ ((c & 4) ? h3b : h3a);
            f[c] = tab2[(h & (TSZ - 1u)) + loff];
        }

        const float w0 = s ? f0 : 1.f - f0;
        const float w1a = 1.f - f1, w2a = 1.f - f2, w3a = 1.f - f3;

        float e0 = 0.f, e1 = 0.f;
        #pragma unroll
        for (int c = 0; c < 8; ++c) {
            const float w = w0 * ((c & 1) ? f1 : w1a)
                               * ((c & 2) ? f2 : w2a)
                               * ((c & 4) ? f3 : w3a);
            e0 = fmaf(w, f[c].x, e0);
            e1 = fmaf(w, f[c].y, e1);
        }

        e0 += __shfl_xor(e0, 1);
        e1 += __shfl_xor(e1, 1);

        if (s == 0)
            ((float2*)encbuf)[(size_t)level * npts + p] = make_float2(e0, e1);
    }

    // ---------------- completion protocol ----------------
    __threadfence();          // release this block's encbuf writes
    __syncthreads();          // all threads' stores issued+fenced
    if (tid == 0)
        lastFlag = (atomicAdd(&counters[chunk], 1) == LVLS - 1);
    __syncthreads();
    if (!lastFlag) return;
    __threadfence();          // acquire: all 16 level-slices now visible

    // ---------------- MLP phase (last arriver only) ----------------
    const int lane = tid & 63;
    const int w    = tid >> 6;                  // 0..3
    const int base = chunk * 128;
    const float* __restrict__ W1w = W1 + 16 * w;
    const float* __restrict__ W2w = W2 + 16 * w;
    const float* __restrict__ W3w = W3 + (16 * w) * 9;
    const float2* __restrict__ e2 = (const float2*)encbuf;

    #pragma unroll
    for (int P = 0; P < 2; ++P) {
        const int pbase = base + 64 * P;

        // cooperative stage: 16 levels x 64 points of enc -> LDS (coalesced)
        #pragma unroll
        for (int r = 0; r < 4; ++r) {
            const int e = tid + 256 * r;        // 0..1023
            const int l = e >> 6, pp = e & 63;
            ((float2*)encS)[e] = e2[(size_t)l * npts + pbase + pp];
        }
        __syncthreads();

        // h1: wave w computes cols [16w,16w+16) for 64 points (1 pt/lane)
        float acc[16];
        #pragma unroll
        for (int j = 0; j < 16; ++j) acc[j] = 0.f;
        #pragma unroll
        for (int l = 0; l < LVLS; ++l) {
            const float2 e = encS[l][lane];
            #pragma unroll
            for (int j = 0; j < 16; ++j) {
                acc[j] = fmaf(e.x, W1w[(2 * l) * 64 + j], acc[j]);
                acc[j] = fmaf(e.y, W1w[(2 * l + 1) * 64 + j], acc[j]);
            }
        }
        #pragma unroll
        for (int j = 0; j < 16; ++j)
            h1S[16 * w + j][lane] = fmaxf(acc[j], 0.f);
        __syncthreads();

        // h2: own 16 cols over all 64 h1 rows
        float g[16];
        #pragma unroll
        for (int j = 0; j < 16; ++j) g[j] = 0.f;
        #pragma unroll
        for (int i = 0; i < 64; ++i) {
            const float hv = h1S[i][lane];
            #pragma unroll
            for (int j = 0; j < 16; ++j)
                g[j] = fmaf(hv, W2w[i * 64 + j], g[j]);
        }
        #pragma unroll
        for (int j = 0; j < 16; ++j) g[j] = fmaxf(g[j], 0.f);

        // partial o[9] over own 16 h2 rows
        float o[9];
        #pragma unroll
        for (int k = 0; k < 9; ++k) o[k] = 0.f;
        #pragma unroll
        for (int j = 0; j < 16; ++j) {
            #pragma unroll
            for (int k = 0; k < 9; ++k)
                o[k] = fmaf(g[j], W3w[j * 9 + k], o[k]);
        }

        __syncthreads();      // h1S reads done; safe to reuse region as oS
        #pragma unroll
        for (int k = 0; k < 9; ++k)
            oS[w][lane][k] = o[k];
        __syncthreads();

        // distributed reduce + store: 576 outputs over 256 threads
        for (int t = tid; t < 576; t += 256) {
            const int p = t / 9;
            const int k = t - 9 * p;
            out[(size_t)9 * (pbase + p) + k] =
                (oS[0][p][k] + oS[1][p][k]) + (oS[2][p][k] + oS[3][p][k]);
        }
        __syncthreads();      // protect encS/oS before pass 2 restage
    }
}

// ---------------- Fallback: fused single kernel (round-1, known-good) ----------------
__global__ __launch_bounds__(256) void hashgrid_mlp_kernel(
    const float* __restrict__ img, const float* __restrict__ pose,
    const float* __restrict__ table, const float* __restrict__ W1,
    const float* __restrict__ W2, const float* __restrict__ W3,
    float* __restrict__ out)
{
    const int n = blockIdx.x * 256 + threadIdx.x;

    const float x0 = img[2 * n], x1 = img[2 * n + 1];
    const float x2 = pose[2 * n], x3 = pose[2 * n + 1];

    const float resv[LVLS] = {16.f, 22.f, 30.f, 42.f, 58.f, 80.f, 110.f, 152.f,
                              210.f, 290.f, 400.f, 553.f, 763.f, 1053.f, 1453.f, 2005.f};

    const float2* __restrict__ tab2 = (const float2*)table;

    float enc[32];

    #pragma unroll
    for (int l = 0; l < LVLS; ++l) {
        const float r = resv[l];
        const float s0 = x0 * r, s1 = x1 * r, s2 = x2 * r, s3 = x3 * r;
        const float p0 = floorf(s0), p1 = floorf(s1), p2 = floorf(s2), p3 = floorf(s3);
        const float f0 = s0 - p0, f1 = s1 - p1, f2 = s2 - p2, f3 = s3 - p3;
        const uint32_t q0 = (uint32_t)p0, q1 = (uint32_t)p1,
                       q2 = (uint32_t)p2, q3 = (uint32_t)p3;

        const uint32_t h1a = q1 * PR1, h1b = h1a + PR1;
        const uint32_t h2a = q2 * PR2, h2b = h2a + PR2;
        const uint32_t h3a = q3 * PR3, h3b = h3a + PR3;
        const float w0a = 1.f - f0, w1a = 1.f - f1, w2a = 1.f - f2, w3a = 1.f - f3;

        float2 feat[16];
        #pragma unroll
        for (int c = 0; c < 16; ++c) {
            const uint32_t h = (q0 + (c & 1))
                             ^ ((c & 2) ? h1b : h1a)
                             ^ ((c & 4) ? h2b : h2a)
                             ^ ((c & 8) ? h3b : h3a);
            const uint32_t idx = (h & (TSZ - 1u)) + (uint32_t)l * TSZ;
            feat[c] = tab2[idx];
        }

        float e0 = 0.f, e1 = 0.f;
        #pragma unroll
        for (int c = 0; c < 16; ++c) {
            const float w = ((c & 1) ? f0 : w0a) * ((c & 2) ? f1 : w1a)
                          * ((c & 4) ? f2 : w2a) * ((c & 8) ? f3 : w3a);
            e0 = fmaf(w, feat[c].x, e0);
            e1 = fmaf(w, feat[c].y, e1);
        }
        enc[2 * l]     = e0;
        enc[2 * l + 1] = e1;
    }

    float h1[64];
    #pragma unroll
    for (int j = 0; j < 64; ++j) h1[j] = 0.f;
    #pragma unroll
    for (int i = 0; i < 32; ++i) {
        const float e = enc[i];
        #pragma unroll
        for (int j = 0; j < 64; ++j) h1[j] = fmaf(e, W1[i * 64 + j], h1[j]);
    }
    #pragma unroll
    for (int j = 0; j < 64; ++j) h1[j] = fmaxf(h1[j], 0.f);

    float h2[64];
    #pragma unroll
    for (int j = 0; j < 64; ++j) h2[j] = 0.f;
    #pragma unroll
    for (int i = 0; i < 64; ++i) {
        const float e = h1[i];
        #pragma unroll
        for (int j = 0; j < 64; ++j) h2[j] = fmaf(e, W2[i * 64 + j], h2[j]);
    }
    #pragma unroll
    for (int j = 0; j < 64; ++j) h2[j] = fmaxf(h2[j], 0.f);

    float o[9];
    #pragma unroll
    for (int j = 0; j < 9; ++j) o[j] = 0.f;
    #pragma unroll
    for (int i = 0; i < 64; ++i) {
        const float e = h2[i];
        #pragma unroll
        for (int j = 0; j < 9; ++j) o[j] = fmaf(e, W3[i * 9 + j], o[j]);
    }
    #pragma unroll
    for (int j = 0; j < 9; ++j) out[9 * n + j] = o[j];
}

extern "C" void kernel_launch(void* const* d_in, const int* in_sizes, int n_in,
                              void* d_out, int out_size, void* d_ws, size_t ws_size,
                              hipStream_t stream) {
    const float* img   = (const float*)d_in[0];
    const float* pose  = (const float*)d_in[1];
    const float* table = (const float*)d_in[2];
    const float* W1    = (const float*)d_in[3];
    const float* W2    = (const float*)d_in[4];
    const float* W3    = (const float*)d_in[5];
    float* out = (float*)d_out;

    const int n = in_sizes[0] / 2;              // number of points
    const int Bper = n / 128;                   // chunks (blocks per level)
    const size_t need_enc = (size_t)n * 32 * sizeof(float);
    const size_t need     = need_enc + (size_t)Bper * sizeof(int);

    if (ws_size >= need && (n % 128) == 0) {
        float* encbuf  = (float*)d_ws;
        int* counters  = (int*)((char*)d_ws + need_enc);
        hipMemsetAsync(counters, 0, (size_t)Bper * sizeof(int), stream);
        hipLaunchKernelGGL(fused_kernel, dim3(Bper * LVLS), dim3(256), 0, stream,
                           img, pose, table, W1, W2, W3,
                           encbuf, counters, out, n, Bper);
    } else {
        hipLaunchKernelGGL(hashgrid_mlp_kernel, dim3((n + 255) / 256), dim3(256), 0, stream,
                           img, pose, table, W1, W2, W3, out);
    }
}

// Round 4
// 148.215 us; speedup vs baseline: 24.9340x; 24.9340x over previous
//
#include <hip/hip_runtime.h>
#include <stdint.h>

#define LVLS 16
#define TSZ (1u << 19)
#define PR1 2654435761u
#define PR2 805459861u
#define PR3 3674653429u

// ---------------- Kernel A: encode v2 — paired dwordx4 gathers ---------------
// Same structure as the frozen round-6 kernel (XCD level-pinning, 2 threads/pt,
// pair shfl reduce, transposed enc write). Gather restructure: PRIME0==1 means
// for even q0 the two dim-0 corners sit at table indices {i, i^1} = an aligned
// 16B pair. Lane s=0 loads each pair as ONE dwordx4 (8 requests, both corners);
// lane s=1 loads its 8 corners only when q0 is odd (predicated). L2 requests
// per point: 16 -> 12 (lines unchanged at ~12). This is the A/B test of
// request-rate-bound vs line-delivery-bound. Request-bound => ~1.3x encode.
__global__ __launch_bounds__(256, 8) void encode_kernel(
    const float* __restrict__ img, const float* __restrict__ pose,
    const float* __restrict__ table, float* __restrict__ encbuf,
    int npts, int Bper)
{
    const int bid = blockIdx.x;
    const int grp = 8 * Bper;
    const int level = (bid % 8) + 8 * (bid / grp);
    const int within = (bid % grp) / 8;

    const int idx = within * 256 + threadIdx.x;
    const int p = idx >> 1;
    const int s = idx & 1;
    if (p >= npts) return;

    const float2 xi = ((const float2*)img)[p];
    const float2 xp = ((const float2*)pose)[p];

    constexpr float resv[LVLS] = {16.f, 22.f, 30.f, 42.f, 58.f, 80.f, 110.f, 152.f,
                                  210.f, 290.f, 400.f, 553.f, 763.f, 1053.f, 1453.f, 2005.f};
    const float rr = resv[level];

    const float s0 = xi.x * rr, s1 = xi.y * rr, s2 = xp.x * rr, s3 = xp.y * rr;
    const float p0f = floorf(s0), p1f = floorf(s1), p2f = floorf(s2), p3f = floorf(s3);
    const float f0 = s0 - p0f, f1 = s1 - p1f, f2 = s2 - p2f, f3 = s3 - p3f;
    const uint32_t q0 = (uint32_t)p0f, q1 = (uint32_t)p1f,
                   q2 = (uint32_t)p2f, q3 = (uint32_t)p3f;

    const uint32_t h1a = q1 * PR1, h1b = h1a + PR1;
    const uint32_t h2a = q2 * PR2, h2b = h2a + PR2;
    const uint32_t h3a = q3 * PR3, h3b = h3a + PR3;
    const uint32_t loff = (uint32_t)level * TSZ;
    const uint32_t msk = TSZ - 1u;

    const float w1a = 1.f - f1, w2a = 1.f - f2, w3a = 1.f - f3;
    float e0 = 0.f, e1 = 0.f;

    if (s == 0) {
        // pair loads: one dwordx4 per dim1-3 corner combo
        const float4* __restrict__ tab4 = (const float4*)table;
        float4 F[8];
        uint32_t selbits = 0;
        #pragma unroll
        for (int c = 0; c < 8; ++c) {
            const uint32_t R = ((c & 1) ? h1b : h1a)
                             ^ ((c & 2) ? h2b : h2a)
                             ^ ((c & 4) ? h3b : h3a);
            const uint32_t i0 = (q0 ^ R) & msk;           // s=0 corner index
            selbits |= (i0 & 1u) << c;                    // which half is ours
            F[c] = tab4[(i0 >> 1) + (loff >> 1)];
        }
        const float wA = 1.f - f0;                        // dim0 bit=0 weight
        const float wB = ((q0 & 1u) == 0u) ? f0 : 0.f;    // partner corner valid
                                                          // only when q0 even
        #pragma unroll
        for (int c = 0; c < 8; ++c) {
            const float wR = ((c & 1) ? f1 : w1a)
                           * ((c & 2) ? f2 : w2a)
                           * ((c & 4) ? f3 : w3a);
            const bool hi = (selbits >> c) & 1u;          // our corner in .zw?
            const float ax = hi ? F[c].z : F[c].x;
            const float ay = hi ? F[c].w : F[c].y;
            const float bx = hi ? F[c].x : F[c].z;
            const float by = hi ? F[c].y : F[c].w;
            e0 = fmaf(wR * wA, ax, e0);
            e1 = fmaf(wR * wA, ay, e1);
            e0 = fmaf(wR * wB, bx, e0);
            e1 = fmaf(wR * wB, by, e1);
        }
    } else if (q0 & 1u) {
        // odd q0: s=1 corner not line-adjacent to s=0 corner -> own 8B loads
        const float2* __restrict__ tab2 = (const float2*)table;
        const uint32_t b1 = q0 + 1u;
        float2 G[8];
        #pragma unroll
        for (int c = 0; c < 8; ++c) {
            const uint32_t R = ((c & 1) ? h1b : h1a)
                             ^ ((c & 2) ? h2b : h2a)
                             ^ ((c & 4) ? h3b : h3a);
            G[c] = tab2[((b1 ^ R) & msk) + loff];
        }
        #pragma unroll
        for (int c = 0; c < 8; ++c) {
            const float wR = ((c & 1) ? f1 : w1a)
                           * ((c & 2) ? f2 : w2a)
                           * ((c & 4) ? f3 : w3a);
            e0 = fmaf(wR * f0, G[c].x, e0);
            e1 = fmaf(wR * f0, G[c].y, e1);
        }
    }

    e0 += __shfl_xor(e0, 1);
    e1 += __shfl_xor(e1, 1);

    if (s == 0)
        ((float2*)encbuf)[(size_t)level * npts + p] = make_float2(e0, e1);
}

// ---------------- Kernel B: MLP (round-2 version, verified 120.1us total) ----
// Block = 256 threads = 4 waves, 128 points. Lane owns point-pair; wave w owns
// cols [16w,16w+16) of h1 AND h2 (weights stay wave-uniform s_load; 16-col
// chunks keep the scalar working set inside the SGPR budget — thread-per-point
// failed on exactly this). h1 exchanged as float2 pairs; distributed epilogue.
__global__ __launch_bounds__(256, 4) void mlp_kernel(
    const float* __restrict__ encbuf, const float* __restrict__ W1,
    const float* __restrict__ W2, const float* __restrict__ W3,
    float* __restrict__ out, int npts)
{
    __shared__ __align__(16) char ldsbuf[64 * 64 * sizeof(float2)];   // 32 KB
    float2 (*h1P)[64]   = (float2 (*)[64])ldsbuf;      // [64 rows][64 pt-pairs]
    float2 (*oS)[64][9] = (float2 (*)[64][9])ldsbuf;   // [4][64][9] (reuse)

    const int lane = threadIdx.x & 63;
    const int w    = __builtin_amdgcn_readfirstlane(threadIdx.x >> 6);   // 0..3
    const int base = blockIdx.x * 128;
    const int pA   = base + lane;
    const int pB   = pA + 64;

    // ---- h1: own 16 columns, both points ----
    const float* __restrict__ W1w = W1 + 16 * w;
    float hA[16], hB[16];
    #pragma unroll
    for (int j = 0; j < 16; ++j) { hA[j] = 0.f; hB[j] = 0.f; }
    const float2* e2 = (const float2*)encbuf;
    #pragma unroll
    for (int l = 0; l < LVLS; ++l) {
        const float2 eA = e2[(size_t)l * npts + pA];
        const float2 eB = e2[(size_t)l * npts + pB];
        #pragma unroll
        for (int j = 0; j < 16; ++j) {
            const float w0 = W1w[(2 * l) * 64 + j];
            const float w1 = W1w[(2 * l + 1) * 64 + j];
            hA[j] = fmaf(eA.x, w0, hA[j]); hA[j] = fmaf(eA.y, w1, hA[j]);
            hB[j] = fmaf(eB.x, w0, hB[j]); hB[j] = fmaf(eB.y, w1, hB[j]);
        }
    }
    #pragma unroll
    for (int j = 0; j < 16; ++j)
        h1P[16 * w + j][lane] = make_float2(fmaxf(hA[j], 0.f), fmaxf(hB[j], 0.f));
    __syncthreads();

    // ---- h2: own 16 columns over all 64 h1 rows, both points ----
    const float* __restrict__ W2w = W2 + 16 * w;
    float gA[16], gB[16];
    #pragma unroll
    for (int j = 0; j < 16; ++j) { gA[j] = 0.f; gB[j] = 0.f; }
    #pragma unroll
    for (int i = 0; i < 64; ++i) {
        const float2 hv = h1P[i][lane];
        #pragma unroll
        for (int j = 0; j < 16; ++j) {
            const float wv = W2w[i * 64 + j];
            gA[j] = fmaf(hv.x, wv, gA[j]);
            gB[j] = fmaf(hv.y, wv, gB[j]);
        }
    }
    #pragma unroll
    for (int j = 0; j < 16; ++j) { gA[j] = fmaxf(gA[j], 0.f); gB[j] = fmaxf(gB[j], 0.f); }

    // ---- partial o[9] over own 16 h2 rows, both points ----
    const float* __restrict__ W3w = W3 + (16 * w) * 9;
    float oA[9], oB[9];
    #pragma unroll
    for (int k = 0; k < 9; ++k) { oA[k] = 0.f; oB[k] = 0.f; }
    #pragma unroll
    for (int j = 0; j < 16; ++j) {
        #pragma unroll
        for (int k = 0; k < 9; ++k) {
            const float wv = W3w[j * 9 + k];
            oA[k] = fmaf(gA[j], wv, oA[k]);
            oB[k] = fmaf(gB[j], wv, oB[k]);
        }
    }

    __syncthreads();   // h1P no longer needed; safe to reuse region as oS

    #pragma unroll
    for (int k = 0; k < 9; ++k)
        oS[w][lane][k] = make_float2(oA[k], oB[k]);
    __syncthreads();

    // ---- distributed reduce + store: 576 float2 outputs over 256 threads ----
    for (int t = threadIdx.x; t < 576; t += 256) {
        const int p = t / 9;
        const int k = t - 9 * p;
        const float2 s0 = oS[0][p][k];
        const float2 s1 = oS[1][p][k];
        const float2 s2 = oS[2][p][k];
        const float2 s3 = oS[3][p][k];
        out[(size_t)9 * (base + p) + k]      = (s0.x + s1.x) + (s2.x + s3.x);
        out[(size_t)9 * (base + p + 64) + k] = (s0.y + s1.y) + (s2.y + s3.y);
    }
}

// ---------------- Fallback: fused single kernel (round-1, known-good) ----------------
__global__ __launch_bounds__(256) void hashgrid_mlp_kernel(
    const float* __restrict__ img, const float* __restrict__ pose,
    const float* __restrict__ table, const float* __restrict__ W1,
    const float* __restrict__ W2, const float* __restrict__ W3,
    float* __restrict__ out)
{
    const int n = blockIdx.x * 256 + threadIdx.x;

    const float x0 = img[2 * n], x1 = img[2 * n + 1];
    const float x2 = pose[2 * n], x3 = pose[2 * n + 1];

    const float resv[LVLS] = {16.f, 22.f, 30.f, 42.f, 58.f, 80.f, 110.f, 152.f,
                              210.f, 290.f, 400.f, 553.f, 763.f, 1053.f, 1453.f, 2005.f};

    const float2* __restrict__ tab2 = (const float2*)table;

    float enc[32];

    #pragma unroll
    for (int l = 0; l < LVLS; ++l) {
        const float r = resv[l];
        const float s0 = x0 * r, s1 = x1 * r, s2 = x2 * r, s3 = x3 * r;
        const float p0 = floorf(s0), p1 = floorf(s1), p2 = floorf(s2), p3 = floorf(s3);
        const float f0 = s0 - p0, f1 = s1 - p1, f2 = s2 - p2, f3 = s3 - p3;
        const uint32_t q0 = (uint32_t)p0, q1 = (uint32_t)p1,
                       q2 = (uint32_t)p2, q3 = (uint32_t)p3;

        const uint32_t h1a = q1 * PR1, h1b = h1a + PR1;
        const uint32_t h2a = q2 * PR2, h2b = h2a + PR2;
        const uint32_t h3a = q3 * PR3, h3b = h3a + PR3;
        const float w0a = 1.f - f0, w1a = 1.f - f1, w2a = 1.f - f2, w3a = 1.f - f3;

        float2 feat[16];
        #pragma unroll
        for (int c = 0; c < 16; ++c) {
            const uint32_t h = (q0 + (c & 1))
                             ^ ((c & 2) ? h1b : h1a)
                             ^ ((c & 4) ? h2b : h2a)
                             ^ ((c & 8) ? h3b : h3a);
            const uint32_t idx = (h & (TSZ - 1u)) + (uint32_t)l * TSZ;
            feat[c] = tab2[idx];
        }

        float e0 = 0.f, e1 = 0.f;
        #pragma unroll
        for (int c = 0; c < 16; ++c) {
            const float w = ((c & 1) ? f0 : w0a) * ((c & 2) ? f1 : w1a)
                          * ((c & 4) ? f2 : w2a) * ((c & 8) ? f3 : w3a);
            e0 = fmaf(w, feat[c].x, e0);
            e1 = fmaf(w, feat[c].y, e1);
        }
        enc[2 * l]     = e0;
        enc[2 * l + 1] = e1;
    }

    float h1[64];
    #pragma unroll
    for (int j = 0; j < 64; ++j) h1[j] = 0.f;
    #pragma unroll
    for (int i = 0; i < 32; ++i) {
        const float e = enc[i];
        #pragma unroll
        for (int j = 0; j < 64; ++j) h1[j] = fmaf(e, W1[i * 64 + j], h1[j]);
    }
    #pragma unroll
    for (int j = 0; j < 64; ++j) h1[j] = fmaxf(h1[j], 0.f);

    float h2[64];
    #pragma unroll
    for (int j = 0; j < 64; ++j) h2[j] = 0.f;
    #pragma unroll
    for (int i = 0; i < 64; ++i) {
        const float e = h1[i];
        #pragma unroll
        for (int j = 0; j < 64; ++j) h2[j] = fmaf(e, W2[i * 64 + j], h2[j]);
    }
    #pragma unroll
    for (int j = 0; j < 64; ++j) h2[j] = fmaxf(h2[j], 0.f);

    float o[9];
    #pragma unroll
    for (int j = 0; j < 9; ++j) o[j] = 0.f;
    #pragma unroll
    for (int i = 0; i < 64; ++i) {
        const float e = h2[i];
        #pragma unroll
        for (int j = 0; j < 9; ++j) o[j] = fmaf(e, W3[i * 9 + j], o[j]);
    }
    #pragma unroll
    for (int j = 0; j < 9; ++j) out[9 * n + j] = o[j];
}

extern "C" void kernel_launch(void* const* d_in, const int* in_sizes, int n_in,
                              void* d_out, int out_size, void* d_ws, size_t ws_size,
                              hipStream_t stream) {
    const float* img   = (const float*)d_in[0];
    const float* pose  = (const float*)d_in[1];
    const float* table = (const float*)d_in[2];
    const float* W1    = (const float*)d_in[3];
    const float* W2    = (const float*)d_in[4];
    const float* W3    = (const float*)d_in[5];
    float* out = (float*)d_out;

    const int n = in_sizes[0] / 2;              // number of points
    const size_t need = (size_t)n * 32 * sizeof(float);

    if (ws_size >= need && (n % 128) == 0 && ((n * 2) % 256) == 0) {
        float* encbuf = (float*)d_ws;
        const int Bper = (n * 2) / 256;         // blocks per level
        hipLaunchKernelGGL(encode_kernel, dim3(Bper * LVLS), dim3(256), 0, stream,
                           img, pose, table, encbuf, n, Bper);
        hipLaunchKernelGGL(mlp_kernel, dim3(n / 128), dim3(256), 0, stream,
                           encbuf, W1, W2, W3, out, n);
    } else {
        hipLaunchKernelGGL(hashgrid_mlp_kernel, dim3((n + 255) / 256), dim3(256), 0, stream,
                           img, pose, table, W1, W2, W3, out);
    }
}